// Round 21
// baseline (48.996 us; speedup 1.0000x reference)
//
#include <hip/hip_runtime.h>
#include <stdint.h>

#define HH 224
#define WW 224
#define NSEAM 7
#define BWIDTH 5
#define BB 256
#define KK 64

// DPP helpers (ctrl must be literal): row_shr:1=0x111 (dst[i]=src[i-1]),
// row_shl:1=0x101 (dst[i]=src[i+1]). Rows = 16 lanes.
#define DPPF_OLD(old, src, ctrl) \
    __int_as_float(__builtin_amdgcn_update_dpp(__float_as_int(old), __float_as_int(src), ctrl, 0xF, 0xF, false))
#define DPPF_Z(src, ctrl) \
    __int_as_float(__builtin_amdgcn_update_dpp(0, __float_as_int(src), ctrl, 0xF, 0xF, true))
#define DPPI_Z(src, ctrl) \
    __builtin_amdgcn_update_dpp(0, (int)(src), ctrl, 0xF, 0xF, true)

// ---------------------------------------------------------------------------
// FUSED single-dispatch kernel: one 1024-thread block (16 waves) per image.
//  Phase A (tid<224): 14 seam DPs — R20 core verbatim: per-row sel bits via
//    cmp+cndmask packed in-register (no ballots/exec-masks), per-chunk
//    4-stage ds_swizzle bit-plane transpose into the proven backtrack word
//    format; backtrack writes paths to LDS pv8/ph8 (R9/R10 u8 layout).
//  Phase B (all 1024): R13's 3-segment label walk, TWO 28-row chunks per
//    thread (cy = tid>>8 and cy+4; same cy 0..7 structure, identical math);
//    vl from pv8, hx from ph8; run-length flush -> packed u64 LDS atomic
//    (fields cnt@42 / sy@21 / sx@0; full-image bounds cnt<2^22, sy,sx<2^21).
//  Phase C (tid<64): unpack acc, divide, write centroids.
// Kills: 2 dispatch gaps, finalize dispatch, paths/gacc global traffic.
// ---------------------------------------------------------------------------
__global__ __launch_bounds__(1024) void fused_kernel(const float* __restrict__ g,
                                                     float* __restrict__ out) {
    __shared__ uint32_t ch[14][226];      // per-row packed sel bits (b0|b1<<16)
    __shared__ unsigned char pv8[HH][8];  // vertical seams: pv8[y][p] = column
    __shared__ unsigned char ph8[8][HH];  // horizontal seams: ph8[p][x] = row
    __shared__ unsigned long long acc[KK];

    const int tid = threadIdx.x;
    const int b   = blockIdx.x;
    if (tid < KK) acc[tid] = 0ull;

    // ---------------- Phase A: 14 DPs on threads 0..223 --------------------
    if (tid < 14 * 16) {
        const int j    = tid & 15;
        const int grp  = tid >> 4;              // 0..13
        const int dir  = grp / 7;
        const int p    = grp % 7;
        const int band0 = 28 * (p + 1) - BWIDTH;
        const int jc   = (j > 10) ? 10 : j;
        const float* gb  = g + (size_t)b * HH * WW;
        const float* gp0 = gb + band0 + jc;                 // dir0: strided rows
        const float* gp1 = gb + (size_t)(band0 + jc) * WW;  // dir1: contiguous
        const unsigned isj0 = (j == 0) ? 1u : 0u;

        float bufA[16], bufB[16], cost;

#define LOADC(BUF, c)                                                       \
    if (dir == 0) {                                                         \
        _Pragma("unroll")                                                   \
        for (int rr = 0; rr < 16; ++rr) BUF[rr] = gp0[((c) * 16 + rr) * WW];\
    } else {                                                                \
        const float4* q4 = reinterpret_cast<const float4*>(gp1 + (c) * 16); \
        float4 t0 = q4[0], t1 = q4[1], t2 = q4[2], t3 = q4[3];              \
        BUF[0] = t0.x;  BUF[1] = t0.y;  BUF[2] = t0.z;  BUF[3] = t0.w;      \
        BUF[4] = t1.x;  BUF[5] = t1.y;  BUF[6] = t1.z;  BUF[7] = t1.w;      \
        BUF[8] = t2.x;  BUF[9] = t2.y;  BUF[10] = t2.z; BUF[11] = t2.w;     \
        BUF[12] = t3.x; BUF[13] = t3.y; BUF[14] = t3.z; BUF[15] = t3.w;     \
    }

// one DP row: min-chain + 2 sel bits in-register (bit-exact R13 semantics).
#define ROWSEL(BUF, rr)                                                     \
    {                                                                       \
        float pm  = DPPF_OLD(cost, cost, 0x111);                            \
        float pv  = DPPF_OLD(cost, cost, 0x101);                            \
        pv = (j >= 10) ? cost : pv;                                         \
        float best = fminf(fminf(pm, cost), pv);                            \
        unsigned cc = (cost == best) ? 1u : 0u;                             \
        unsigned b0 = (pm == best) ? isj0 : cc;                             \
        unsigned b1 = (pm == best) ? 0u : (cc ^ 1u);                        \
        cost = best - (BUF)[rr];                                            \
        selLo |= b0 << (rr);                                                \
        selHi |= b1 << (rr);                                                \
    }

// 16x16 1-bit-plane transpose within each 16-lane group (R20-proven).
#define TR16(x)                                                             \
    {                                                                       \
        unsigned pp;                                                        \
        pp = (unsigned)__builtin_amdgcn_ds_swizzle((int)(x), 0x201F);       \
        x = (j & 8) ? ((x & 0xFF00u) | ((pp >> 8) & 0x00FFu))               \
                    : ((x & 0x00FFu) | ((pp << 8) & 0xFF00u));              \
        pp = (unsigned)__builtin_amdgcn_ds_swizzle((int)(x), 0x101F);       \
        x = (j & 4) ? ((x & 0xF0F0u) | ((pp >> 4) & 0x0F0Fu))               \
                    : ((x & 0x0F0Fu) | ((pp << 4) & 0xF0F0u));              \
        pp = (unsigned)__builtin_amdgcn_ds_swizzle((int)(x), 0x081F);       \
        x = (j & 2) ? ((x & 0xCCCCu) | ((pp >> 2) & 0x3333u))               \
                    : ((x & 0x3333u) | ((pp << 2) & 0xCCCCu));              \
        pp = (unsigned)__builtin_amdgcn_ds_swizzle((int)(x), 0x041F);       \
        x = (j & 1) ? ((x & 0xAAAAu) | ((pp >> 1) & 0x5555u))               \
                    : ((x & 0x5555u) | ((pp << 1) & 0xAAAAu));              \
    }

#define PROCC(BUF, c)                                                       \
    {                                                                       \
        unsigned selLo = 0u, selHi = 0u;                                    \
        _Pragma("unroll")                                                   \
        for (int rr = 0; rr < 16; ++rr) ROWSEL(BUF, rr)                     \
        TR16(selLo)                                                         \
        TR16(selHi)                                                         \
        ch[grp][(c) * 16 + j] = selLo | (selHi << 16);                      \
    }

        LOADC(bufA, 0);
        LOADC(bufB, 1);
        {
            unsigned selLo = 0u, selHi = 0u;
            cost = -bufA[0];
#pragma unroll
            for (int rr = 1; rr < 16; ++rr) ROWSEL(bufA, rr)
            TR16(selLo)
            TR16(selHi)
            ch[grp][j] = selLo | (selHi << 16);
        }
        LOADC(bufA, 2);
        PROCC(bufB, 1);
        LOADC(bufB, 3);

#pragma unroll 1
        for (int c2 = 2; c2 <= 12; c2 += 2) {
            PROCC(bufA, c2);
            if (c2 + 2 < 14) LOADC(bufA, c2 + 2);
            PROCC(bufB, c2 + 1);
            if (c2 + 3 < 14) LOADC(bufB, c2 + 3);
        }

        // final argmin across 11 lanes (first-min == lexicographic min)
        float rc = (j <= 10) ? cost : INFINITY;
        int   ri = (j <= 10) ? j : 15;
#define REDSTEP(ctrl)                                                        \
        {                                                                    \
            float oc = DPPF_Z(rc, ctrl);                                     \
            int   oi = DPPI_Z(ri, ctrl);                                     \
            bool t = (oc < rc) || (oc == rc && oi < ri);                     \
            rc = t ? oc : rc; ri = t ? oi : ri;                              \
        }
        REDSTEP(0x128) REDSTEP(0x124) REDSTEP(0x122) REDSTEP(0x121)
#undef REDSTEP

        int pos = ri;
        const bool wr = (j == 0);
        if (wr) {
            if (dir == 0) pv8[HH - 1][p] = (unsigned char)(band0 + pos);
            else          ph8[p][HH - 1] = (unsigned char)(band0 + pos);
        }

        // backtrack (R13-proven decode); paths land in LDS
#pragma unroll 1
        for (int c = 13; c >= 0; --c) {
            uint32_t w[16];
#pragma unroll
            for (int rr = 0; rr < 16; ++rr) w[rr] = ch[grp][c * 16 + rr];
#pragma unroll
            for (int rr = 15; rr >= 0; --rr) {
                int r = c * 16 + rr;
                if (r >= 1) {
                    uint32_t ww = w[rr];
                    int sel = (int)((ww >> pos) & 1u) | (int)((ww >> (pos + 15)) & 2u);
                    pos += sel - 1;
                    if (wr) {
                        if (dir == 0) pv8[r - 1][p] = (unsigned char)(band0 + pos);
                        else          ph8[p][r - 1] = (unsigned char)(band0 + pos);
                    }
                }
            }
        }
#undef LOADC
#undef ROWSEL
#undef TR16
#undef PROCC
    }

    __syncthreads();

    // ---------------- Phase B: labels + centroid partials ------------------
    // thread = (x = tid&255); two 28-row chunks: cy = tid>>8 and cy+4.
    // R13's 3-segment static walk per chunk (identical label math).
    const int x = tid & 255;
    if (x < WW) {
        int basev = 0, kv = 0, inv = 0;
        if (x >= 23) {
            int q = x - 23, k = q / 28, r = q - k * 28;
            if (k > 6) basev = 7;
            else { inv = (r <= 10) ? 1 : 0; basev = k + (r > 10 ? 1 : 0); kv = k; }
        }
        float* mb = out + (size_t)BB * KK * 2 + (size_t)b * HH * WW + x;

#pragma unroll
        for (int ov = 0; ov < 2; ++ov) {
            const int cy = (tid >> 8) + 4 * ov;      // 0..3 then 4..7
            const int y0 = cy * 28;
            const int hA = (cy >= 1) ? (int)ph8[cy - 1][x] : 0;   // t 0..5
            const int hB = (cy <= 6) ? (int)ph8[cy][x] : 0;       // t 23..27
            int cur = -1, ys = y0;

#define FLUSH(yend)                                                          \
            {                                                                \
                unsigned cnt = (unsigned)((yend) - ys);                      \
                unsigned sy  = (unsigned)((ys + (yend) - 1) * ((yend) - ys) / 2);\
                unsigned sx  = (unsigned)x * cnt;                            \
                atomicAdd(&acc[cur], ((unsigned long long)cnt << 42) |       \
                                     ((unsigned long long)sy << 21) |        \
                                     (unsigned long long)sx);                \
            }
#define ROW(t, HLEXPR)                                                       \
            {                                                                \
                const int y = y0 + (t);                                      \
                int vl = basev + ((inv && (int)pv8[y][kv] <= x) ? 1 : 0);    \
                int lab = vl + 8 * (HLEXPR);                                 \
                mb[y * WW] = (float)lab;                                     \
                if (lab != cur) { if (cur >= 0) FLUSH(y); cur = lab; ys = y; }\
            }
#pragma unroll
            for (int t = 0; t < 6; ++t)
                ROW(t, (cy >= 1) ? (cy - 1 + ((hA <= y0 + t) ? 1 : 0)) : 0)
#pragma unroll
            for (int t = 6; t < 23; ++t)
                ROW(t, cy)
#pragma unroll
            for (int t = 23; t < 28; ++t)
                ROW(t, (cy <= 6) ? (cy + ((hB <= y0 + t) ? 1 : 0)) : 7)
            FLUSH(y0 + 28)
#undef ROW
#undef FLUSH
        }
    }
    __syncthreads();

    // ---------------- Phase C: finalize centroids --------------------------
    if (tid < KK) {
        unsigned long long sv = acc[tid];
        float cnt = (float)(unsigned)(sv >> 42);
        float sy  = (float)(unsigned)((sv >> 21) & 0x1FFFFFu);
        float sx  = (float)(unsigned)(sv & 0x1FFFFFu);
        float c = fmaxf(cnt, 1e-6f);
        float2 r; r.x = sy / c; r.y = sx / c;
        *reinterpret_cast<float2*>(out + (size_t)b * KK * 2 + tid * 2) = r;
    }
}

extern "C" void kernel_launch(void* const* d_in, const int* in_sizes, int n_in,
                              void* d_out, int out_size, void* d_ws, size_t ws_size,
                              hipStream_t stream) {
    const float* g = (const float*)d_in[1];
    float* out = (float*)d_out;
    fused_kernel<<<BB, 1024, 0, stream>>>(g, out);
}

// Round 22
// 45.302 us; speedup vs baseline: 1.0815x; 1.0815x over previous
//
#include <hip/hip_runtime.h>
#include <stdint.h>

#define HH 224
#define WW 224
#define NSEAM 7
#define BWIDTH 5
#define BB 256
#define KK 64
#define YCH 8
#define YROWS (HH / YCH)

// DPP helpers (ctrl must be literal): row_shr:1=0x111 (dst[i]=src[i-1]),
// row_shl:1=0x101 (dst[i]=src[i+1]). Rows = 16 lanes.
#define DPPF_OLD(old, src, ctrl) \
    __int_as_float(__builtin_amdgcn_update_dpp(__float_as_int(old), __float_as_int(src), ctrl, 0xF, 0xF, false))
#define DPPF_Z(src, ctrl) \
    __int_as_float(__builtin_amdgcn_update_dpp(0, __float_as_int(src), ctrl, 0xF, 0xF, true))
#define DPPI_Z(src, ctrl) \
    __builtin_amdgcn_update_dpp(0, (int)(src), ctrl, 0xF, 0xF, true)

// ---------------------------------------------------------------------------
// Kernel 1: seam DP (R20-proven, best known). Per-row sel bits via
// cmp+cndmask packed in-register (no ballots / exec masks / SALU); per-chunk
// 4-stage ds_swizzle bit-plane transpose into the proven backtrack word
// format (b0 | b1<<16). sel semantics bit-identical to R13 (absmax=0).
// Dir-major mapping, dir1 float4 loads, depth-2 A/B buffers, 224 blocks.
// Zeroes gacc.
// ---------------------------------------------------------------------------
__global__ __launch_bounds__(256) void dp_kernel(const float* __restrict__ g,
                                                 int* __restrict__ paths,
                                                 unsigned long long* __restrict__ gacc) {
    __shared__ uint32_t ch[16][226];   // per-row packed sel bits (b0 | b1<<16)
    __shared__ int      pth[16][226];  // backtracked path positions

    {   // zero global centroid accumulators (label kernel runs after us)
        int t = blockIdx.x * 256 + threadIdx.x;
        if (t < BB * KK) gacc[t] = 0ull;
    }

    const int j   = threadIdx.x & 15;
    const int grp = threadIdx.x >> 4;
    const int gid = blockIdx.x * 16 + grp;
    const int dir = gid / (BB * NSEAM);         // block-uniform (1792/16=112)
    const int rem = gid - dir * (BB * NSEAM);
    const int b   = rem / NSEAM;
    const int p   = rem - b * NSEAM;
    const int band0 = 28 * (p + 1) - BWIDTH;
    const int jc  = (j > 10) ? 10 : j;          // clamp junk lanes
    const float* gb  = g + (size_t)b * HH * WW;
    const float* gp0 = gb + band0 + jc;                 // dir0: strided rows
    const float* gp1 = gb + (size_t)(band0 + jc) * WW;  // dir1: contiguous cols
    const unsigned isj0 = (j == 0) ? 1u : 0u;   // sel bit0 when jm wins at j==0

    float bufA[16], bufB[16], cost;

#define LOADC(BUF, c)                                                       \
    if (dir == 0) {                                                         \
        _Pragma("unroll")                                                   \
        for (int rr = 0; rr < 16; ++rr) BUF[rr] = gp0[((c) * 16 + rr) * WW];\
    } else {                                                                \
        const float4* q4 = reinterpret_cast<const float4*>(gp1 + (c) * 16); \
        float4 t0 = q4[0], t1 = q4[1], t2 = q4[2], t3 = q4[3];              \
        BUF[0] = t0.x;  BUF[1] = t0.y;  BUF[2] = t0.z;  BUF[3] = t0.w;      \
        BUF[4] = t1.x;  BUF[5] = t1.y;  BUF[6] = t1.z;  BUF[7] = t1.w;      \
        BUF[8] = t2.x;  BUF[9] = t2.y;  BUF[10] = t2.z; BUF[11] = t2.w;     \
        BUF[12] = t3.x; BUF[13] = t3.y; BUF[14] = t3.z; BUF[15] = t3.w;     \
    }

// one DP row: min-chain + 2 sel bits accumulated in-register.
// bit-exact R13 semantics: best = fminf(fminf(pm,cost),ppv);
// b0 = pm==best ? isj0 : (cost==best); b1 = pm==best ? 0 : !(cost==best).
#define ROWSEL(BUF, rr)                                                     \
    {                                                                       \
        float pm  = DPPF_OLD(cost, cost, 0x111);                            \
        float pv  = DPPF_OLD(cost, cost, 0x101);                            \
        pv = (j >= 10) ? cost : pv;                                         \
        float best = fminf(fminf(pm, cost), pv);                            \
        unsigned cc = (cost == best) ? 1u : 0u;                             \
        unsigned b0 = (pm == best) ? isj0 : cc;                             \
        unsigned b1 = (pm == best) ? 0u : (cc ^ 1u);                        \
        cost = best - (BUF)[rr];                                            \
        selLo |= b0 << (rr);                                                \
        selHi |= b1 << (rr);                                                \
    }

// 16x16 1-bit-plane transpose across the 16 lanes of a group (R20-proven):
// after TR16, lane r bit q == (orig lane q bit r). 4-stage XOR butterfly.
#define TR16(x)                                                             \
    {                                                                       \
        unsigned pp;                                                        \
        pp = (unsigned)__builtin_amdgcn_ds_swizzle((int)(x), 0x201F);       \
        x = (j & 8) ? ((x & 0xFF00u) | ((pp >> 8) & 0x00FFu))               \
                    : ((x & 0x00FFu) | ((pp << 8) & 0xFF00u));              \
        pp = (unsigned)__builtin_amdgcn_ds_swizzle((int)(x), 0x101F);       \
        x = (j & 4) ? ((x & 0xF0F0u) | ((pp >> 4) & 0x0F0Fu))               \
                    : ((x & 0x0F0Fu) | ((pp << 4) & 0xF0F0u));              \
        pp = (unsigned)__builtin_amdgcn_ds_swizzle((int)(x), 0x081F);       \
        x = (j & 2) ? ((x & 0xCCCCu) | ((pp >> 2) & 0x3333u))               \
                    : ((x & 0x3333u) | ((pp << 2) & 0xCCCCu));              \
        pp = (unsigned)__builtin_amdgcn_ds_swizzle((int)(x), 0x041F);       \
        x = (j & 1) ? ((x & 0xAAAAu) | ((pp >> 1) & 0x5555u))               \
                    : ((x & 0x5555u) | ((pp << 1) & 0xAAAAu));              \
    }

// full 16-row chunk: accumulate sel planes, transpose, store row-words.
// lane r's word covers row c*16+r; bits 11-15 come from junk lanes but are
// never read (pos <= 10). Row 0's word (c==0, lane 0) is unread by backtrack.
#define PROCC(BUF, c)                                                       \
    {                                                                       \
        unsigned selLo = 0u, selHi = 0u;                                    \
        _Pragma("unroll")                                                   \
        for (int rr = 0; rr < 16; ++rr) ROWSEL(BUF, rr)                     \
        TR16(selLo)                                                         \
        TR16(selHi)                                                         \
        ch[grp][(c) * 16 + j] = selLo | (selHi << 16);                      \
    }

    // ---- prologue: chunks 0 (row-0 init) and 1; loads 2 chunks ahead ----
    LOADC(bufA, 0);
    LOADC(bufB, 1);
    {
        unsigned selLo = 0u, selHi = 0u;
        cost = -bufA[0];
#pragma unroll
        for (int rr = 1; rr < 16; ++rr) ROWSEL(bufA, rr)
        TR16(selLo)
        TR16(selHi)
        ch[grp][j] = selLo | (selHi << 16);
    }
    LOADC(bufA, 2);
    PROCC(bufB, 1);
    LOADC(bufB, 3);

#pragma unroll 1
    for (int c2 = 2; c2 <= 12; c2 += 2) {
        PROCC(bufA, c2);
        if (c2 + 2 < 14) LOADC(bufA, c2 + 2);
        PROCC(bufB, c2 + 1);
        if (c2 + 3 < 14) LOADC(bufB, c2 + 3);
    }

    // final argmin across 11 lanes, first-min tie-break == lexicographic min
    float rc = (j <= 10) ? cost : INFINITY;
    int   ri = (j <= 10) ? j : 15;
#define REDSTEP(ctrl)                                                        \
    {                                                                        \
        float oc = DPPF_Z(rc, ctrl);                                         \
        int   oi = DPPI_Z(ri, ctrl);                                         \
        bool t = (oc < rc) || (oc == rc && oi < ri);                         \
        rc = t ? oc : rc; ri = t ? oi : ri;                                  \
    }
    REDSTEP(0x128) REDSTEP(0x124) REDSTEP(0x122) REDSTEP(0x121)
#undef REDSTEP

    int pos = ri;
    if (j == 0) pth[grp][HH - 1] = band0 + pos;

    // backtrack (R13-proven): broadcast LDS reads prefetched per chunk
#pragma unroll 1
    for (int c = 13; c >= 0; --c) {
        uint32_t w[16];
#pragma unroll
        for (int rr = 0; rr < 16; ++rr) w[rr] = ch[grp][c * 16 + rr];
#pragma unroll
        for (int rr = 15; rr >= 0; --rr) {
            int r = c * 16 + rr;
            if (r >= 1) {
                uint32_t ww = w[rr];
                int sel = (int)((ww >> pos) & 1u) | (int)((ww >> (pos + 15)) & 2u);
                pos += sel - 1;
                if (j == 0) pth[grp][r - 1] = band0 + pos;
            }
        }
    }

    // coalesced path write; layout [b][dir*7+p][224]
    int* op = paths + (size_t)(b * 14 + dir * NSEAM + p) * HH;
#pragma unroll 1
    for (int c = 0; c < 14; ++c) op[c * 16 + j] = pth[grp][c * 16 + j];

#undef LOADC
#undef ROWSEL
#undef TR16
#undef PROCC
}

// ---------------------------------------------------------------------------
// Kernel 2: labels + centroid partials (R13-proven, unchanged). Grid = B*8.
// 3-segment static walk; vl = basev + (in-band && pv[y][kv] <= x).
// Run-length flush -> packed u64 LDS atomic; block partials -> global
// atomicAdd. Fields cnt:22@42 / sy:21@21 / sx:21@0, carry-free; all
// integers < 2^22 exact in f32.
// ---------------------------------------------------------------------------
__global__ __launch_bounds__(256) void label_kernel(const int* __restrict__ paths,
                                                    float* __restrict__ out,
                                                    unsigned long long* __restrict__ gacc) {
    const int b  = blockIdx.x >> 3;
    const int cy = blockIdx.x & 7;
    const int y0 = cy * YROWS;

    __shared__ unsigned char vpc[NSEAM][YROWS];
    __shared__ unsigned long long acc[KK];

    const int* pb = paths + (size_t)b * 14 * HH;
    for (int i = threadIdx.x; i < NSEAM * YROWS; i += 256) {
        int q = i / YROWS, r = i - q * YROWS;
        vpc[q][r] = (unsigned char)pb[q * HH + y0 + r];
    }
    if (threadIdx.x < KK) acc[threadIdx.x] = 0ull;
    __syncthreads();

    const int x = threadIdx.x;
    if (x < WW) {
        int basev = 0, kv = 0, inv = 0;
        if (x >= 23) {
            int q = x - 23, k = q / 28, r = q - k * 28;
            if (k > 6) basev = 7;
            else { inv = (r <= 10) ? 1 : 0; basev = k + (r > 10 ? 1 : 0); kv = k; }
        }
        const int hA = (cy >= 1) ? pb[(NSEAM + cy - 1) * HH + x] : 0;
        const int hB = (cy <= 6) ? pb[(NSEAM + cy) * HH + x] : 0;

        float* mb = out + (size_t)BB * KK * 2 + (size_t)b * HH * WW + x;
        int cur = -1, ys = y0;

#define FLUSH(yend)                                                          \
        {                                                                    \
            unsigned cnt = (unsigned)((yend) - ys);                          \
            unsigned sy  = (unsigned)((ys + (yend) - 1) * ((yend) - ys) / 2);\
            unsigned sx  = (unsigned)x * cnt;                                \
            atomicAdd(&acc[cur], ((unsigned long long)cnt << 42) |           \
                                 ((unsigned long long)sy << 21) |            \
                                 (unsigned long long)sx);                    \
        }
#define ROW(t, HLEXPR)                                                       \
        {                                                                    \
            const int y = y0 + (t);                                          \
            int vl = basev + ((inv && (int)vpc[kv][t] <= x) ? 1 : 0);        \
            int lab = vl + 8 * (HLEXPR);                                     \
            mb[y * WW] = (float)lab;                                         \
            if (lab != cur) { if (cur >= 0) FLUSH(y); cur = lab; ys = y; }   \
        }
#pragma unroll
        for (int t = 0; t < 6; ++t)
            ROW(t, (cy >= 1) ? (cy - 1 + ((hA <= y0 + t) ? 1 : 0)) : 0)
#pragma unroll
        for (int t = 6; t < 23; ++t)
            ROW(t, cy)
#pragma unroll
        for (int t = 23; t < 28; ++t)
            ROW(t, (cy <= 6) ? (cy + ((hB <= y0 + t) ? 1 : 0)) : 7)
        FLUSH(y0 + YROWS)
#undef ROW
#undef FLUSH
    }
    __syncthreads();

    if (threadIdx.x < KK) {
        unsigned long long v = acc[threadIdx.x];
        if (v) atomicAdd(&gacc[(size_t)b * KK + threadIdx.x], v);
    }
}

// ---------------------------------------------------------------------------
// Kernel 3: finalize centroids. 16384 regions; unpack, divide, float2 store.
// ---------------------------------------------------------------------------
__global__ __launch_bounds__(256) void finalize_kernel(const unsigned long long* __restrict__ gacc,
                                                       float* __restrict__ out) {
    int i = blockIdx.x * 256 + threadIdx.x;
    unsigned long long sv = gacc[i];
    float cnt = (float)(unsigned)(sv >> 42);
    float sy  = (float)(unsigned)((sv >> 21) & 0x1FFFFFu);
    float sx  = (float)(unsigned)(sv & 0x1FFFFFu);
    float c = fmaxf(cnt, 1e-6f);
    float2 r; r.x = sy / c; r.y = sx / c;
    *reinterpret_cast<float2*>(out + (size_t)i * 2) = r;
}

extern "C" void kernel_launch(void* const* d_in, const int* in_sizes, int n_in,
                              void* d_out, int out_size, void* d_ws, size_t ws_size,
                              hipStream_t stream) {
    const float* g = (const float*)d_in[1];
    float* out = (float*)d_out;
    int* paths = (int*)d_ws;                                        // 3,211,264 B
    unsigned long long* gacc =
        (unsigned long long*)((char*)d_ws + (size_t)BB * 14 * HH * 4);   // 128 KiB

    dp_kernel<<<(BB * 14) / 16, 256, 0, stream>>>(g, paths, gacc);  // 224 blocks
    label_kernel<<<BB * YCH, 256, 0, stream>>>(paths, out, gacc);
    finalize_kernel<<<(BB * KK) / 256, 256, 0, stream>>>(gacc, out);
}